// Round 16
// baseline (72.979 us; speedup 1.0000x reference)
//
#include <hip/hip_runtime.h>
#include <hip/hip_fp16.h>

#define NQ 10
#define NSAMP 16384
#define BN_EPS 1e-5f
#define SGN 0x80008000u

// ---------------- packed f16 helpers: h2 = (sample A, sample B) ----------------
union H2U { __half2 h; unsigned u; };
__device__ __forceinline__ __half2 u2h(unsigned u) { H2U t; t.u = u; return t.h; }
__device__ __forceinline__ unsigned h2u(__half2 h) { H2U t; t.h = h; return t.u; }

// compile-time xor shuffle for the inlined gates/epilogue:
// masks 1,2,3 DPP quad_perm (VALU); 4..0x1F ds_swizzle; 0x20 ds_bpermute(a20)
template<int M>
__device__ __forceinline__ unsigned shufu(unsigned v, int a20) {
  if constexpr (M == 1) {
    return (unsigned)__builtin_amdgcn_mov_dpp((int)v, 0xB1, 0xF, 0xF, true);
  } else if constexpr (M == 2) {
    return (unsigned)__builtin_amdgcn_mov_dpp((int)v, 0x4E, 0xF, 0xF, true);
  } else if constexpr (M == 3) {
    return (unsigned)__builtin_amdgcn_mov_dpp((int)v, 0x1B, 0xF, 0xF, true);
  } else if constexpr (M < 32) {
    return (unsigned)__builtin_amdgcn_ds_swizzle((int)v, (M << 10) | 0x1F);
  } else {
    return (unsigned)__builtin_amdgcn_ds_bpermute(a20, (int)v);
  }
}
template<int M>
__device__ __forceinline__ __half2 shufh(__half2 v, int a20) {
  return u2h(shufu<M>(h2u(v), a20));
}

// -------- mask tables (deferred CNOT-chain relabeling) — trace-verified R4-R15 --------
// Index bit b (9..0) = wire (9-b). Lane holds bits 9..4, regs bits 3..0.
// 16 h2 regs: reg index r = stored index bits 3..0; h2 halves = two samples.
// Single-qubit gates within a layer commute -> each layer reordered:
// pure-lane gates (MR=0, HR=0) first via a RUNTIME loop, then the rest inlined.
constexpr int ML_[3][10] = {
  {0x20,0x10,0x08,0x04,0x02,0x01, 0,   0,   0,   0},
  {0x30,0x18,0x0C,0x06,0x03,0x01, 0,   0,   0,   0},
  {0x28,0x14,0x0A,0x05,0x02,0x01, 0,   0,   0,   0}};
constexpr int MR_[3][10] = {
  {0,0,0,0,0,0,   0x8,0x4,0x2,0x1},
  {0,0,0,0,0,0x8, 0xC,0x6,0x3,0x1},
  {0,0,0,0,0x8,0x4,0xA,0x5,0x2,0x1}};
constexpr int HR_[3][10] = {
  {0,0,0,0,0,0, 0x8,0x4,0x2,0x1},
  {0,0,0,0,0,0, 0x8,0xC,0xE,0xF},
  {0,0,0,0,0,0, 0x8,0x4,0xA,0x5}};
constexpr int EHL[10] = {0x20,0x30,0x18,0x0C,0x26,0x33,0x19,0x0C,0x26,0x33};

// packed 6-bit tables for the 9 runtime-looped pure-lane gates
// (L1 q0-4, then L2 q0-3): partner mask, hi-parity mask, cph index
constexpr unsigned long long PK6(int a0,int a1,int a2,int a3,int a4,
                                 int a5,int a6,int a7,int a8) {
  unsigned long long v = 0;
  const int a[9] = {a0,a1,a2,a3,a4,a5,a6,a7,a8};
  for (int i = 0; i < 9; ++i) v |= (unsigned long long)(unsigned)a[i] << (6 * i);
  return v;
}
constexpr unsigned long long ML64 = PK6(0x30,0x18,0x0C,0x06,0x03, 0x28,0x14,0x0A,0x05);
constexpr unsigned long long HL64 = PK6(0x20,0x30,0x38,0x3C,0x3E, 0x20,0x10,0x28,0x14);
constexpr unsigned long long CI64 = PK6(0,1,2,3,4, 10,11,12,13);

constexpr int hibit4(int m) {
  return m >= 8 ? 8 : (m >= 4 ? 4 : (m >= 2 ? 2 : (m ? 1 : 0)));
}
constexpr bool par4(int v) { return ((v >> 3 & 1) ^ (v >> 2 & 1) ^ (v >> 1 & 1) ^ (v & 1)) != 0; }

// amp update: 3 pk-FMA + 1 pk-mul per component
__device__ __forceinline__ void updh(__half2& ar, __half2& ai, __half2 br, __half2 bi,
                                     __half2 WR, __half2 AWI, __half2 NAWI,
                                     __half2 AVR, __half2 VI, __half2 NVI) {
  const __half2 a0r = ar, a0i = ai;
  ar = __hfma2(WR, a0r, __hfma2(AWI, a0i, __hfma2(AVR, br, __hmul2(NVI, bi))));
  ai = __hfma2(WR, a0i, __hfma2(NAWI, a0r, __hfma2(AVR, bi, __hmul2(VI, br))));
}

// inlined SU(2) gate (compile-time masks) for the non-pure-lane gates
template<int ML, int MR, int HR>
__device__ __forceinline__ void gateh(__half2* __restrict__ Hr, __half2* __restrict__ Hi,
                                      unsigned sgnw, int a20, uint4 cp) {
  const unsigned swi = cp.y ^ sgnw;
  const unsigned svr = cp.z ^ sgnw;
  const __half2 WR  = u2h(cp.x);
  const __half2 VI  = u2h(cp.w);
  const __half2 NVI = u2h(cp.w ^ SGN);
  const __half2 WI0 = u2h(swi);
  const __half2 WI1 = u2h(swi ^ SGN);
  const __half2 VR0 = u2h(svr);
  const __half2 VR1 = u2h(svr ^ SGN);

  if constexpr (MR == 0) {
    #pragma unroll
    for (int r = 0; r < 16; ++r) {
      const __half2 br = shufh<ML>(Hr[r], a20);
      const __half2 bi = shufh<ML>(Hi[r], a20);
      const bool p = par4(r & HR);
      updh(Hr[r], Hi[r], br, bi, WR, p ? WI1 : WI0, p ? WI0 : WI1,
           p ? VR1 : VR0, VI, NVI);
    }
  } else {
    constexpr int HB = hibit4(MR);
    #pragma unroll
    for (int r = 0; r < 16; ++r) {
      if (!(r & HB)) {
        const int r2 = r ^ MR;
        __half2 b0r, b0i, b1r, b1i;
        if constexpr (ML != 0) {
          b0r = shufh<ML>(Hr[r2], a20); b0i = shufh<ML>(Hi[r2], a20);
          b1r = shufh<ML>(Hr[r],  a20); b1i = shufh<ML>(Hi[r],  a20);
        } else {
          b0r = Hr[r2]; b0i = Hi[r2]; b1r = Hr[r]; b1i = Hi[r];
        }
        const bool pa = par4(r & HR);
        updh(Hr[r], Hi[r], b0r, b0i, WR, pa ? WI1 : WI0, pa ? WI0 : WI1,
             pa ? VR1 : VR0, VI, NVI);
        const bool pb = par4(r2 & HR);
        updh(Hr[r2], Hi[r2], b1r, b1i, WR, pb ? WI1 : WI0, pb ? WI0 : WI1,
             pb ? VR1 : VR0, VI, NVI);
      }
    }
  }
}

template<int L, int Q>
__device__ __forceinline__ void rotgh(const uint4* __restrict__ cph,
                                      __half2* Hr, __half2* Hi,
                                      unsigned sgnw, int a20) {
  const uint4 cp = cph[(L - 1) * 10 + Q];
  gateh<ML_[L][Q], MR_[L][Q], HR_[L][Q]>(Hr, Hi, sgnw, a20, cp);
}

// per-qubit encoded+layer0 2-vector: (alpha,beta) = U0q * (cos, sin)
__device__ __forceinline__ void enc2(const float4 g, float xq,
                                     float& ar, float& ai, float& br, float& bi) {
  const float t = xq * 0.5f;
  const float sq = __sinf(t), cq = __cosf(t);
  ar = g.x * cq - g.z * sq;
  ai = g.y * cq + g.w * sq;
  br = g.z * cq + g.x * sq;
  bi = g.w * cq - g.y * sq;
}
__device__ __forceinline__ void cmul(float& zr, float& zi,
                                     float xr, float xi, float yr, float yi) {
  zr = xr * yr - xi * yi;
  zi = xr * yi + xi * yr;
}

// f32 progressive tensor-product build (encoding + folded layer-0) for one sample
__device__ __forceinline__ void build_state(const float* __restrict__ xrow,
                                            const float4* __restrict__ cg,
                                            int lane, float* __restrict__ sr,
                                            float* __restrict__ si) {
  float lr, li;
  {
    float ar, ai, br, bi;
    enc2(cg[0], xrow[0], ar, ai, br, bi);
    lr = (lane & 32) ? br : ar;
    li = (lane & 32) ? bi : ai;
  }
  #pragma unroll
  for (int q = 1; q < 6; ++q) {
    float ar, ai, br, bi;
    enc2(cg[q], xrow[q], ar, ai, br, bi);
    const int bit = 1 << (5 - q);
    const float tr = (lane & bit) ? br : ar;
    const float ti = (lane & bit) ? bi : ai;
    const float nr = lr * tr - li * ti;
    const float ni = lr * ti + li * tr;
    lr = nr; li = ni;
  }
  float ar, ai, br, bi;
  float t2r[2], t2i[2], t4r[4], t4i[4], t8r[8], t8i[8];
  enc2(cg[6], xrow[6], ar, ai, br, bi);
  cmul(t2r[0], t2i[0], lr, li, ar, ai);
  cmul(t2r[1], t2i[1], lr, li, br, bi);
  enc2(cg[7], xrow[7], ar, ai, br, bi);
  #pragma unroll
  for (int j = 0; j < 2; ++j) {
    cmul(t4r[2*j+0], t4i[2*j+0], t2r[j], t2i[j], ar, ai);
    cmul(t4r[2*j+1], t4i[2*j+1], t2r[j], t2i[j], br, bi);
  }
  enc2(cg[8], xrow[8], ar, ai, br, bi);
  #pragma unroll
  for (int j = 0; j < 4; ++j) {
    cmul(t8r[2*j+0], t8i[2*j+0], t4r[j], t4i[j], ar, ai);
    cmul(t8r[2*j+1], t8i[2*j+1], t4r[j], t4i[j], br, bi);
  }
  enc2(cg[9], xrow[9], ar, ai, br, bi);
  #pragma unroll
  for (int j = 0; j < 8; ++j) {
    cmul(sr[2*j+0], si[2*j+0], t8r[j], t8i[j], ar, ai);
    cmul(sr[2*j+1], si[2*j+1], t8r[j], t8i[j], br, bi);
  }
}

// K0: fused SU(2) RY*RX*RZ per (layer,qubit); also zeroes the stats accumulators
__global__ void coef_kernel(const float* __restrict__ params, float* __restrict__ coef,
                            unsigned* __restrict__ cph, float* __restrict__ stats) {
  int g = threadIdx.x;
  if (g < 20) stats[g] = 0.f;
  if (g < 30) {
    float t0 = params[g * 3 + 0] * 0.5f;
    float t1 = params[g * 3 + 1] * 0.5f;
    float t2 = params[g * 3 + 2] * 0.5f;
    float sa, ca, s2, c2, s3, c3;
    __sincosf(t0, &sa, &ca);
    __sincosf(t1, &s2, &c2);
    __sincosf(t2, &s3, &c3);
    float A = c3 * c2, Bv = s3 * s2, C = s3 * c2, D = c3 * s2;
    float wr = A * ca + Bv * sa;
    float wi = Bv * ca - A * sa;
    float vr = C * ca - D * sa;
    float vi = -(C * sa + D * ca);
    coef[g * 4 + 0] = wr;
    coef[g * 4 + 1] = wi;
    coef[g * 4 + 2] = vr;
    coef[g * 4 + 3] = vi;
    if (g >= 10) {
      int gi = g - 10;
      cph[gi * 4 + 0] = h2u(__floats2half2_rn(wr, wr));
      cph[gi * 4 + 1] = h2u(__floats2half2_rn(wi, wi));
      cph[gi * 4 + 2] = h2u(__floats2half2_rn(vr, vr));
      cph[gi * 4 + 3] = h2u(__floats2half2_rn(vi, vi));
    }
  }
}

// K1: one wave64 per TWO samples (h2 lo = sample A, hi = sample B); fused BN stats.
// Code-size-minimized: encode loop (1 static copy), 9 pure-lane gates in a
// runtime loop (1 static copy), 11 reg/DPP gates inlined (no DS shuffles).
__global__ __launch_bounds__(256) void circuit_kernel(const float* __restrict__ x,
                                                      const float* __restrict__ coef,
                                                      const uint4* __restrict__ cph,
                                                      float* __restrict__ out,
                                                      float* __restrict__ stats) {
  const int lane = threadIdx.x & 63;
  const int wv = threadIdx.x >> 6;
  const int wid = __builtin_amdgcn_readfirstlane(
      (int)((blockIdx.x * blockDim.x + threadIdx.x) >> 6));
  const float4* cg = (const float4*)coef;
  const int a20 = (lane ^ 0x20) << 2;

  // sign words for the inlined gates: SMASK 0x3F (L1 q5-9), 0x2A, 0x15 (L2)
  const unsigned s3F = (__builtin_popcount(lane & 0x3F) & 1) ? 0u : SGN;
  const unsigned s2A = (__builtin_popcount(lane & 0x2A) & 1) ? 0u : SGN;
  const unsigned s15 = (__builtin_popcount(lane & 0x15) & 1) ? 0u : SGN;

  // ---- build two samples' product states (f32), merge into h2 halves ----
  const int sA = wid * 2;
  __half2 Hr[16], Hi[16];
  #pragma unroll 1
  for (int j = 0; j < 2; ++j) {
    float sr[16], si[16];
    build_state(x + (sA + j) * NQ, cg, lane, sr, si);
    #pragma unroll
    for (int r = 0; r < 16; ++r) {
      const unsigned pr = h2u(__floats2half2_rn(sr[r], sr[r])) & 0xFFFFu;
      const unsigned pi = h2u(__floats2half2_rn(si[r], si[r])) & 0xFFFFu;
      if (j == 0) { Hr[r] = u2h(pr); Hi[r] = u2h(pi); }
      else { Hr[r] = u2h(h2u(Hr[r]) | (pr << 16)); Hi[r] = u2h(h2u(Hi[r]) | (pi << 16)); }
    }
  }

  // ---- runtime loop over pure-lane gates (MR=0, HR=0), bpermute-based ----
  // executes g=0..4 (L1 q0-4) now; g=5..8 (L2 q0-3) after the L1 inlined gates
  auto lane_loop = [&](int g0, int g1) {
    #pragma unroll 1
    for (int g = g0; g < g1; ++g) {
      const unsigned ml = (unsigned)((ML64 >> (6 * g)) & 0x3F);
      const unsigned hl = (unsigned)((HL64 >> (6 * g)) & 0x3F);
      const int ci = (int)((CI64 >> (6 * g)) & 0x3F);
      const uint4 cp = cph[ci];
      const int addr = (int)((unsigned)(lane ^ (int)ml) << 2);
      const unsigned sgnw = (__builtin_popcount(lane & hl) & 1) ? 0u : SGN;
      const __half2 WR  = u2h(cp.x);
      const __half2 VI  = u2h(cp.w);
      const __half2 NVI = u2h(cp.w ^ SGN);
      const __half2 WI  = u2h(cp.y ^ sgnw);
      const __half2 NWI = u2h(cp.y ^ sgnw ^ SGN);
      const __half2 VR  = u2h(cp.z ^ sgnw);
      #pragma unroll
      for (int r = 0; r < 16; ++r) {
        const __half2 br = u2h((unsigned)__builtin_amdgcn_ds_bpermute(addr, (int)h2u(Hr[r])));
        const __half2 bi = u2h((unsigned)__builtin_amdgcn_ds_bpermute(addr, (int)h2u(Hi[r])));
        updh(Hr[r], Hi[r], br, bi, WR, WI, NWI, VR, VI, NVI);
      }
    }
  };

  // ---- layer 1: lane gates (loop) then q5-q9 (inlined; DPP/reg only) ----
  lane_loop(0, 5);
  rotgh<1,5>(cph, Hr, Hi, s3F, a20);
  rotgh<1,6>(cph, Hr, Hi, s3F, a20);
  rotgh<1,7>(cph, Hr, Hi, s3F, a20);
  rotgh<1,8>(cph, Hr, Hi, s3F, a20);
  rotgh<1,9>(cph, Hr, Hi, s3F, a20);

  // ---- layer 2: lane gates (loop) then q4-q9 (inlined; DPP/reg only) ----
  lane_loop(5, 9);
  rotgh<2,4>(cph, Hr, Hi, s2A, a20);
  rotgh<2,5>(cph, Hr, Hi, s15, a20);
  rotgh<2,6>(cph, Hr, Hi, s2A, a20);
  rotgh<2,7>(cph, Hr, Hi, s15, a20);
  rotgh<2,8>(cph, Hr, Hi, s2A, a20);
  rotgh<2,9>(cph, Hr, Hi, s15, a20);

  // ---- epilogue: 5 Walsh sums, both samples at once (h2 halves) ----
  __half2 T = u2h(0u), S8 = T, SC = T, S6 = T, S3 = T;
  #pragma unroll
  for (int r = 0; r < 16; ++r) {
    const __half2 P = __hfma2(Hr[r], Hr[r], __hmul2(Hi[r], Hi[r]));
    T = __hadd2(T, P);
    S8 = par4(r & 0x8) ? __hsub2(S8, P) : __hadd2(S8, P);
    SC = par4(r & 0xC) ? __hsub2(SC, P) : __hadd2(SC, P);
    S6 = par4(r & 0x6) ? __hsub2(S6, P) : __hadd2(S6, P);
    S3 = par4(r & 0x3) ? __hsub2(S3, P) : __hadd2(S3, P);
  }
  const __half2 S[10] = {T, T, T, T, T, T, S8, SC, S6, S3};
  __half2 e[10];
  #pragma unroll
  for (int q = 0; q < 10; ++q) {
    const bool neg = (__builtin_popcount(lane & EHL[q]) & 1) != 0;
    e[q] = u2h(h2u(S[q]) ^ (neg ? SGN : 0u));
  }
  #pragma unroll
  for (int q = 0; q < 10; ++q) {
    e[q] = __hadd2(e[q], shufh<0x20>(e[q], a20));
    e[q] = __hadd2(e[q], shufh<0x10>(e[q], a20));
    e[q] = __hadd2(e[q], shufh<0x08>(e[q], a20));
    e[q] = __hadd2(e[q], shufh<0x04>(e[q], a20));
    e[q] = __hadd2(e[q], shufh<0x02>(e[q], a20));
    e[q] = __hadd2(e[q], shufh<0x01>(e[q], a20));
  }

  // ---- store + fused BN stats (block reduce -> 20 atomics/block) ----
  __shared__ float red[4][20];
  if (lane == 0) {
    #pragma unroll
    for (int q = 0; q < 10; ++q) {
      const float ea = __half2float(__low2half(e[q]));
      const float eb = __half2float(__high2half(e[q]));
      out[sA * NQ + q]       = ea;
      out[(sA + 1) * NQ + q] = eb;
      red[wv][q]      = ea + eb;
      red[wv][10 + q] = ea * ea + eb * eb;
    }
  }
  __syncthreads();
  const int tid = threadIdx.x;
  if (tid < 20) {
    float ssum = red[0][tid] + red[1][tid] + red[2][tid] + red[3][tid];
    atomicAdd(&stats[tid], ssum);
  }
}

// K2: BatchNorm apply; finalizes mean/rstd from fused sums per thread.
__global__ __launch_bounds__(256) void bn_kernel(float* __restrict__ out,
                                                 const float* __restrict__ stats,
                                                 const float* __restrict__ gamma,
                                                 const float* __restrict__ beta) {
  int i = blockIdx.x * 256 + threadIdx.x;
  if (i < NSAMP * NQ) {
    int q = i % NQ;
    float mean = stats[q] * (1.f / NSAMP);
    float var = stats[10 + q] * (1.f / NSAMP) - mean * mean;
    if (var < 0.f) var = 0.f;
    float rstd = rsqrtf(var + BN_EPS);
    float v = out[i];
    out[i] = gamma[q] * (v - mean) * rstd + beta[q];
  }
}

extern "C" void kernel_launch(void* const* d_in, const int* in_sizes, int n_in,
                              void* d_out, int out_size, void* d_ws, size_t ws_size,
                              hipStream_t stream) {
  const float* x      = (const float*)d_in[0];
  const float* params = (const float*)d_in[1];
  const float* gamma  = (const float*)d_in[2];
  const float* beta   = (const float*)d_in[3];
  float* out = (float*)d_out;
  float* stats = (float*)d_ws;                        // [0..9]=sum, [10..19]=sum^2
  float* coef = (float*)d_ws + 32;                    // 30 gates * 4 f32
  unsigned* cph = (unsigned*)((float*)d_ws + 160);    // 20 gates * 4 packed (16B-aligned)

  coef_kernel<<<1, 32, 0, stream>>>(params, coef, cph, stats);
  circuit_kernel<<<NSAMP / 8, 256, 0, stream>>>(x, coef, (const uint4*)cph, out, stats);
  bn_kernel<<<(NSAMP * NQ + 255) / 256, 256, 0, stream>>>(out, stats, gamma, beta);
}

// Round 17
// 66.442 us; speedup vs baseline: 1.0984x; 1.0984x over previous
//
#include <hip/hip_runtime.h>
#include <hip/hip_fp16.h>

#define NQ 10
#define NSAMP 16384
#define BN_EPS 1e-5f
#define SGN 0x80008000u

// ---------------- packed f16 helpers: h2 = (sample A, sample B) ----------------
union H2U { __half2 h; unsigned u; };
__device__ __forceinline__ __half2 u2h(unsigned u) { H2U t; t.u = u; return t.h; }
__device__ __forceinline__ unsigned h2u(__half2 h) { H2U t; t.h = h; return t.u; }
__device__ __forceinline__ __half2 hpack(float lo, float hi) {
  return __floats2half2_rn(lo, hi);
}

// masks < 0x20: ds_swizzle immediate xor; >= 0x20: ds_bpermute w/ precomputed addr
template<int M>
__device__ __forceinline__ unsigned shufu(unsigned v, int a30, int a28, int a20) {
  if constexpr (M < 32) {
    return (unsigned)__builtin_amdgcn_ds_swizzle((int)v, (M << 10) | 0x1F);
  } else {
    const int addr = (M == 0x30) ? a30 : (M == 0x28) ? a28 : a20;
    return (unsigned)__builtin_amdgcn_ds_bpermute(addr, (int)v);
  }
}
template<int M>
__device__ __forceinline__ __half2 shufh(__half2 v, int a30, int a28, int a20) {
  return u2h(shufu<M>(h2u(v), a30, a28, a20));
}

// -------- mask tables (deferred CNOT-chain relabeling) — trace-verified R4-R16 --------
// Index bit b (9..0) = wire (9-b). Lane holds bits 9..4, regs bits 3..0.
// 16 h2 regs: reg index r = stored index bits 3..0; h2 halves = two samples.
constexpr int ML_[3][10] = {
  {0x20,0x10,0x08,0x04,0x02,0x01, 0,   0,   0,   0},
  {0x30,0x18,0x0C,0x06,0x03,0x01, 0,   0,   0,   0},
  {0x28,0x14,0x0A,0x05,0x02,0x01, 0,   0,   0,   0}};
constexpr int MR_[3][10] = {
  {0,0,0,0,0,0,   0x8,0x4,0x2,0x1},
  {0,0,0,0,0,0x8, 0xC,0x6,0x3,0x1},
  {0,0,0,0,0x8,0x4,0xA,0x5,0x2,0x1}};
constexpr int HR_[3][10] = {
  {0,0,0,0,0,0, 0x8,0x4,0x2,0x1},
  {0,0,0,0,0,0, 0x8,0xC,0xE,0xF},
  {0,0,0,0,0,0, 0x8,0x4,0xA,0x5}};
// Epilogue sign masks (row b of C^{-3}), trace-verified in R4.
constexpr int EHL[10] = {0x20,0x30,0x18,0x0C,0x26,0x33,0x19,0x0C,0x26,0x33};
// Epilogue reg-parity masks for q6..9: 0x8, 0xC, 0x6, 0x3 (accumulated directly).

// distinct HL masks for layers 1,2 -> precomputed sign-word index
constexpr int SMASK[12] = {0x20,0x30,0x38,0x3C,0x3E,0x3F, 0x20,0x10,0x28,0x14,0x2A,0x15};
constexpr int SIX[2][10] = {{0,1,2,3,4,5,5,5,5,5}, {6,7,8,9,10,11,10,11,10,11}};

constexpr int hibit4(int m) {
  return m >= 8 ? 8 : (m >= 4 ? 4 : (m >= 2 ? 2 : (m ? 1 : 0)));
}
constexpr bool par4(int v) { return ((v >> 3 & 1) ^ (v >> 2 & 1) ^ (v >> 1 & 1) ^ (v & 1)) != 0; }

// amp update: 3 pk-FMA + 1 pk-mul per component
__device__ __forceinline__ void updh(__half2& ar, __half2& ai, __half2 br, __half2 bi,
                                     __half2 WR, __half2 AWI, __half2 NAWI,
                                     __half2 AVR, __half2 VI, __half2 NVI) {
  const __half2 a0r = ar, a0i = ai;
  ar = __hfma2(WR, a0r, __hfma2(AWI, a0i, __hfma2(AVR, br, __hmul2(NVI, bi))));
  ai = __hfma2(WR, a0i, __hfma2(NAWI, a0r, __hfma2(AVR, bi, __hmul2(VI, br))));
}

// SU(2) gate on 16-h2 state (both samples share all signs).
// sgnw = lane-parity sign word (0 if hi-parity lane, else 0x80008000).
template<int ML, int MR, int HR>
__device__ __forceinline__ void gateh(__half2* __restrict__ Hr, __half2* __restrict__ Hi,
                                      unsigned sgnw, int a30, int a28, int a20, uint4 cp) {
  const unsigned swi = cp.y ^ sgnw;
  const unsigned svr = cp.z ^ sgnw;
  const __half2 WR  = u2h(cp.x);
  const __half2 VI  = u2h(cp.w);
  const __half2 NVI = u2h(cp.w ^ SGN);
  const __half2 WI0 = u2h(swi);            // awi for reg-parity 0
  const __half2 WI1 = u2h(swi ^ SGN);      // awi for reg-parity 1 (== -WI0)
  const __half2 VR0 = u2h(svr);
  const __half2 VR1 = u2h(svr ^ SGN);

  if constexpr (MR == 0) {                 // pure lane-bit gate
    #pragma unroll
    for (int r = 0; r < 16; ++r) {
      const __half2 br = shufh<ML>(Hr[r], a30, a28, a20);
      const __half2 bi = shufh<ML>(Hi[r], a30, a28, a20);
      const bool p = par4(r & HR);
      updh(Hr[r], Hi[r], br, bi, WR, p ? WI1 : WI0, p ? WI0 : WI1,
           p ? VR1 : VR0, VI, NVI);
    }
  } else {                                 // reg pair (+ maybe lane)
    constexpr int HB = hibit4(MR);
    #pragma unroll
    for (int r = 0; r < 16; ++r) {
      if (!(r & HB)) {
        const int r2 = r ^ MR;
        __half2 b0r, b0i, b1r, b1i;
        if constexpr (ML != 0) {
          b0r = shufh<ML>(Hr[r2], a30, a28, a20); b0i = shufh<ML>(Hi[r2], a30, a28, a20);
          b1r = shufh<ML>(Hr[r],  a30, a28, a20); b1i = shufh<ML>(Hi[r],  a30, a28, a20);
        } else {
          b0r = Hr[r2]; b0i = Hi[r2]; b1r = Hr[r]; b1i = Hi[r];
        }
        const bool pa = par4(r & HR);
        updh(Hr[r], Hi[r], b0r, b0i, WR, pa ? WI1 : WI0, pa ? WI0 : WI1,
             pa ? VR1 : VR0, VI, NVI);
        const bool pb = par4(r2 & HR);
        updh(Hr[r2], Hi[r2], b1r, b1i, WR, pb ? WI1 : WI0, pb ? WI0 : WI1,
             pb ? VR1 : VR0, VI, NVI);
      }
    }
  }
}

template<int L, int Q>
__device__ __forceinline__ void rotgh(const uint4* __restrict__ cph,
                                      __half2* Hr, __half2* Hi,
                                      const unsigned* __restrict__ sgnv,
                                      int a30, int a28, int a20) {
  const uint4 cp = cph[(L - 1) * 10 + Q];
  gateh<ML_[L][Q], MR_[L][Q], HR_[L][Q]>(Hr, Hi, sgnv[SIX[L - 1][Q]], a30, a28, a20, cp);
}

// per-qubit encoded+layer0 2-vector: (alpha,beta) = U0q * (cos, sin)
__device__ __forceinline__ void enc2(const float4 g, float xq,
                                     float& ar, float& ai, float& br, float& bi) {
  const float t = xq * 0.5f;
  const float sq = __sinf(t), cq = __cosf(t);
  ar = g.x * cq - g.z * sq;
  ai = g.y * cq + g.w * sq;
  br = g.z * cq + g.x * sq;
  bi = g.w * cq - g.y * sq;
}
__device__ __forceinline__ void cmul(float& zr, float& zi,
                                     float xr, float xi, float yr, float yi) {
  zr = xr * yr - xi * yi;
  zi = xr * yi + xi * yr;
}

// f32 progressive tensor-product build (encoding + folded layer-0) for one sample
__device__ __forceinline__ void build_state(const float* __restrict__ xrow,
                                            const float4* __restrict__ cg,
                                            int lane, float* __restrict__ sr,
                                            float* __restrict__ si) {
  float lr, li;
  {
    float ar, ai, br, bi;
    enc2(cg[0], xrow[0], ar, ai, br, bi);
    lr = (lane & 32) ? br : ar;
    li = (lane & 32) ? bi : ai;
  }
  #pragma unroll
  for (int q = 1; q < 6; ++q) {
    float ar, ai, br, bi;
    enc2(cg[q], xrow[q], ar, ai, br, bi);
    const int bit = 1 << (5 - q);
    const float tr = (lane & bit) ? br : ar;
    const float ti = (lane & bit) ? bi : ai;
    const float nr = lr * tr - li * ti;
    const float ni = lr * ti + li * tr;
    lr = nr; li = ni;
  }
  float ar, ai, br, bi;
  float t2r[2], t2i[2], t4r[4], t4i[4], t8r[8], t8i[8];
  enc2(cg[6], xrow[6], ar, ai, br, bi);
  cmul(t2r[0], t2i[0], lr, li, ar, ai);
  cmul(t2r[1], t2i[1], lr, li, br, bi);
  enc2(cg[7], xrow[7], ar, ai, br, bi);
  #pragma unroll
  for (int j = 0; j < 2; ++j) {
    cmul(t4r[2*j+0], t4i[2*j+0], t2r[j], t2i[j], ar, ai);
    cmul(t4r[2*j+1], t4i[2*j+1], t2r[j], t2i[j], br, bi);
  }
  enc2(cg[8], xrow[8], ar, ai, br, bi);
  #pragma unroll
  for (int j = 0; j < 4; ++j) {
    cmul(t8r[2*j+0], t8i[2*j+0], t4r[j], t4i[j], ar, ai);
    cmul(t8r[2*j+1], t8i[2*j+1], t4r[j], t4i[j], br, bi);
  }
  enc2(cg[9], xrow[9], ar, ai, br, bi);
  #pragma unroll
  for (int j = 0; j < 8; ++j) {
    cmul(sr[2*j+0], si[2*j+0], t8r[j], t8i[j], ar, ai);
    cmul(sr[2*j+1], si[2*j+1], t8r[j], t8i[j], br, bi);
  }
}

// K0: fused SU(2) RY*RX*RZ per (layer,qubit); also zeroes the stats accumulators
__global__ void coef_kernel(const float* __restrict__ params, float* __restrict__ coef,
                            unsigned* __restrict__ cph, float* __restrict__ stats) {
  int g = threadIdx.x;
  if (g < 20) stats[g] = 0.f;
  if (g < 30) {
    float t0 = params[g * 3 + 0] * 0.5f;
    float t1 = params[g * 3 + 1] * 0.5f;
    float t2 = params[g * 3 + 2] * 0.5f;
    float sa, ca, s2, c2, s3, c3;
    __sincosf(t0, &sa, &ca);
    __sincosf(t1, &s2, &c2);
    __sincosf(t2, &s3, &c3);
    float A = c3 * c2, Bv = s3 * s2, C = s3 * c2, D = c3 * s2;
    float wr = A * ca + Bv * sa;
    float wi = Bv * ca - A * sa;
    float vr = C * ca - D * sa;
    float vi = -(C * sa + D * ca);
    coef[g * 4 + 0] = wr;
    coef[g * 4 + 1] = wi;
    coef[g * 4 + 2] = vr;
    coef[g * 4 + 3] = vi;
    if (g >= 10) {
      int gi = g - 10;
      cph[gi * 4 + 0] = h2u(hpack(wr, wr));
      cph[gi * 4 + 1] = h2u(hpack(wi, wi));
      cph[gi * 4 + 2] = h2u(hpack(vr, vr));
      cph[gi * 4 + 3] = h2u(hpack(vi, vi));
    }
  }
}

// K1: one wave64 per TWO samples (h2 lo = sample A, hi = sample B); fused BN stats.
__global__ __launch_bounds__(256) void circuit_kernel(const float* __restrict__ x,
                                                      const float* __restrict__ coef,
                                                      const uint4* __restrict__ cph,
                                                      float* __restrict__ out,
                                                      float* __restrict__ stats) {
  const int lane = threadIdx.x & 63;
  const int wv = threadIdx.x >> 6;
  const int wid = __builtin_amdgcn_readfirstlane(
      (int)((blockIdx.x * blockDim.x + threadIdx.x) >> 6));
  const float4* cg = (const float4*)coef;

  const int a30 = (lane ^ 0x30) << 2;
  const int a28 = (lane ^ 0x28) << 2;
  const int a20 = (lane ^ 0x20) << 2;

  unsigned sgnv[12];
  #pragma unroll
  for (int k = 0; k < 12; ++k)
    sgnv[k] = (__builtin_popcount(lane & SMASK[k]) & 1) ? 0u : SGN;

  // ---- build two samples' product states (f32), pack into h2 halves ----
  const int sA = wid * 2, sB = wid * 2 + 1;
  float srA[16], siA[16], srB[16], siB[16];
  build_state(x + sA * NQ, cg, lane, srA, siA);
  build_state(x + sB * NQ, cg, lane, srB, siB);
  __half2 Hr[16], Hi[16];
  #pragma unroll
  for (int r = 0; r < 16; ++r) {
    Hr[r] = hpack(srA[r], srB[r]);
    Hi[r] = hpack(siA[r], siB[r]);
  }

  // ---- layers 1,2 fused rotations (both samples per pk op); CNOTs free ----
  rotgh<1,0>(cph,Hr,Hi,sgnv,a30,a28,a20); rotgh<1,1>(cph,Hr,Hi,sgnv,a30,a28,a20);
  rotgh<1,2>(cph,Hr,Hi,sgnv,a30,a28,a20); rotgh<1,3>(cph,Hr,Hi,sgnv,a30,a28,a20);
  rotgh<1,4>(cph,Hr,Hi,sgnv,a30,a28,a20); rotgh<1,5>(cph,Hr,Hi,sgnv,a30,a28,a20);
  rotgh<1,6>(cph,Hr,Hi,sgnv,a30,a28,a20); rotgh<1,7>(cph,Hr,Hi,sgnv,a30,a28,a20);
  rotgh<1,8>(cph,Hr,Hi,sgnv,a30,a28,a20); rotgh<1,9>(cph,Hr,Hi,sgnv,a30,a28,a20);

  rotgh<2,0>(cph,Hr,Hi,sgnv,a30,a28,a20); rotgh<2,1>(cph,Hr,Hi,sgnv,a30,a28,a20);
  rotgh<2,2>(cph,Hr,Hi,sgnv,a30,a28,a20); rotgh<2,3>(cph,Hr,Hi,sgnv,a30,a28,a20);
  rotgh<2,4>(cph,Hr,Hi,sgnv,a30,a28,a20); rotgh<2,5>(cph,Hr,Hi,sgnv,a30,a28,a20);
  rotgh<2,6>(cph,Hr,Hi,sgnv,a30,a28,a20); rotgh<2,7>(cph,Hr,Hi,sgnv,a30,a28,a20);
  rotgh<2,8>(cph,Hr,Hi,sgnv,a30,a28,a20); rotgh<2,9>(cph,Hr,Hi,sgnv,a30,a28,a20);

  // ---- epilogue: 5 Walsh sums, both samples at once (h2 halves) ----
  __half2 T = u2h(0u), S8 = T, SC = T, S6 = T, S3 = T;
  #pragma unroll
  for (int r = 0; r < 16; ++r) {
    const __half2 P = __hfma2(Hr[r], Hr[r], __hmul2(Hi[r], Hi[r]));
    T = __hadd2(T, P);
    S8 = par4(r & 0x8) ? __hsub2(S8, P) : __hadd2(S8, P);
    SC = par4(r & 0xC) ? __hsub2(SC, P) : __hadd2(SC, P);
    S6 = par4(r & 0x6) ? __hsub2(S6, P) : __hadd2(S6, P);
    S3 = par4(r & 0x3) ? __hsub2(S3, P) : __hadd2(S3, P);
  }
  const __half2 S[10] = {T, T, T, T, T, T, S8, SC, S6, S3};
  __half2 e[10];
  #pragma unroll
  for (int q = 0; q < 10; ++q) {
    const bool neg = (__builtin_popcount(lane & EHL[q]) & 1) != 0;
    e[q] = u2h(h2u(S[q]) ^ (neg ? SGN : 0u));
  }
  #pragma unroll
  for (int q = 0; q < 10; ++q) {
    e[q] = __hadd2(e[q], shufh<0x20>(e[q], a30, a28, a20));
    e[q] = __hadd2(e[q], shufh<0x10>(e[q], a30, a28, a20));
    e[q] = __hadd2(e[q], shufh<0x08>(e[q], a30, a28, a20));
    e[q] = __hadd2(e[q], shufh<0x04>(e[q], a30, a28, a20));
    e[q] = __hadd2(e[q], shufh<0x02>(e[q], a30, a28, a20));
    e[q] = __hadd2(e[q], shufh<0x01>(e[q], a30, a28, a20));
  }

  // ---- store + fused BN stats (block reduce -> 20 atomics/block) ----
  __shared__ float red[4][20];
  if (lane == 0) {
    #pragma unroll
    for (int q = 0; q < 10; ++q) {
      const float ea = __half2float(__low2half(e[q]));
      const float eb = __half2float(__high2half(e[q]));
      out[sA * NQ + q] = ea;
      out[sB * NQ + q] = eb;
      red[wv][q]      = ea + eb;
      red[wv][10 + q] = ea * ea + eb * eb;
    }
  }
  __syncthreads();
  const int tid = threadIdx.x;
  if (tid < 20) {
    float ssum = red[0][tid] + red[1][tid] + red[2][tid] + red[3][tid];
    atomicAdd(&stats[tid], ssum);
  }
}

// K2: BatchNorm apply; finalizes mean/rstd from fused sums per thread.
__global__ __launch_bounds__(256) void bn_kernel(float* __restrict__ out,
                                                 const float* __restrict__ stats,
                                                 const float* __restrict__ gamma,
                                                 const float* __restrict__ beta) {
  int i = blockIdx.x * 256 + threadIdx.x;
  if (i < NSAMP * NQ) {
    int q = i % NQ;
    float mean = stats[q] * (1.f / NSAMP);
    float var = stats[10 + q] * (1.f / NSAMP) - mean * mean;
    if (var < 0.f) var = 0.f;
    float rstd = rsqrtf(var + BN_EPS);
    float v = out[i];
    out[i] = gamma[q] * (v - mean) * rstd + beta[q];
  }
}

extern "C" void kernel_launch(void* const* d_in, const int* in_sizes, int n_in,
                              void* d_out, int out_size, void* d_ws, size_t ws_size,
                              hipStream_t stream) {
  const float* x      = (const float*)d_in[0];
  const float* params = (const float*)d_in[1];
  const float* gamma  = (const float*)d_in[2];
  const float* beta   = (const float*)d_in[3];
  float* out = (float*)d_out;
  float* stats = (float*)d_ws;                        // [0..9]=sum, [10..19]=sum^2
  float* coef = (float*)d_ws + 32;                    // 30 gates * 4 f32
  unsigned* cph = (unsigned*)((float*)d_ws + 160);    // 20 gates * 4 packed (16B-aligned)

  coef_kernel<<<1, 32, 0, stream>>>(params, coef, cph, stats);
  circuit_kernel<<<NSAMP / 8, 256, 0, stream>>>(x, coef, (const uint4*)cph, out, stats);
  bn_kernel<<<(NSAMP * NQ + 255) / 256, 256, 0, stream>>>(out, stats, gamma, beta);
}